// Round 9
// baseline (156.198 us; speedup 1.0000x reference)
//
#include <hip/hip_runtime.h>

// Cuboid (windowed) self-attention, B=2,T=8,H=W=64,C=256, HEADS=8, WS=8.
// Bw = 128 windows, N = 512 tokens/window, dh = 32, bh = window*8+head (1024).
// k_prep: weightsT->bf16, fold scale*log2e into Q cols.
// k_qkv : window-partition + x@qkv_w. ONE barrier (post A-stage); B-fragments read
//         directly from L2-resident wqT (no B LDS stage, no per-kk barriers).
//         Q/K epilogue transposed through per-wave LDS -> 16B stores.
//         Layouts (consumed by k_attn):
//         Qs/Ks[bh][t(16)][cb(4)][lane(32)][8]  (t=n>>5, cb=d>>3, lane=n&31, elem=d&7)
//         Vs[bh][mt(16)][kv(2)][h(2)][d(32)][8] (m = mt*32+kv*16+8h+j)
// k_attn: per bh, 4 waves x 128 q. K+V staged once in 64KB linear LDS.
//         32x32x16 MFMAs, S^T = K x Q^T; no-max softmax (shift-invariant, fp32-safe);
//         P -> PV B-operand via v_permlane32_swap_b32 (zero LDS); O in-register.
// k_proj: O@proj_w + bias, window reverse, fp32 out. Same barrier-free B-direct GEMM.

typedef __bf16 bf16x8 __attribute__((ext_vector_type(8)));
typedef float f32x4 __attribute__((ext_vector_type(4)));
typedef float f32x16 __attribute__((ext_vector_type(16)));

#define NTOK 512
#define DH 32
#define CDIM 256
#define C3 768

__device__ __forceinline__ unsigned short f2b(float f) {
  unsigned u = __builtin_bit_cast(unsigned, f);
  unsigned r = u + 0x7fffu + ((u >> 16) & 1u);   // RNE, inputs finite
  return (unsigned short)(r >> 16);
}

__device__ __forceinline__ unsigned pk2(float a, float b) {
  __bf16 x = (__bf16)a, y = (__bf16)b;
  return (unsigned)__builtin_bit_cast(unsigned short, x) |
         ((unsigned)__builtin_bit_cast(unsigned short, y) << 16);
}

// ---------------- kernel 0: weight prep ----------------
__global__ void k_prep(const float* __restrict__ qkv_w, const float* __restrict__ proj_w,
                       unsigned short* __restrict__ wqT, unsigned short* __restrict__ wpT) {
  const float QS = 0.2550540254f;  // 32^-0.5 * log2(e)
  int idx = blockIdx.x * 256 + threadIdx.x;
  int stride = gridDim.x * 256;
  for (int i = idx; i < C3 * CDIM; i += stride) {
    int n = i >> 8, kk = i & 255;
    float f = qkv_w[kk * C3 + n];
    if (n < 256) f *= QS;
    wqT[i] = f2b(f);
  }
  for (int i = idx; i < CDIM * CDIM; i += stride) {
    int n = i >> 8, kk = i & 255;
    wpT[i] = f2b(proj_w[kk * CDIM + n]);
  }
}

// ---------------- kernel 1: QKV GEMM (window partition fused) ----------------
// grid 512 blocks, 256 thr. LDS: A full-K [128][264] bf16 (67584B) +
// per-wave transpose tile [16][88] ushort (4 x 2816B). Total 78848B.
__global__ __launch_bounds__(256, 2) void k_qkv(
    const float* __restrict__ x, const unsigned short* __restrict__ wqT,
    unsigned short* __restrict__ qo, unsigned short* __restrict__ ko,
    unsigned short* __restrict__ vo) {
  extern __shared__ char smem[];
  unsigned short (*As)[264] = (unsigned short (*)[264])smem;
  int tid = threadIdx.x;
  int mtile = blockIdx.x;
  int bw = mtile >> 2;
  int n0 = (mtile & 3) << 7;
  int bb = bw >> 6, hi = (bw >> 3) & 7, wi = bw & 7;

  {  // stage A: rows gathered by window partition, fp32 -> bf16
    int row = tid >> 1;
    int n = n0 + row;
    int tt = n >> 6, ii = (n >> 3) & 7, jj = n & 7;
    const float* src = x + ((((long)(bb * 8 + tt)) * 64 + (hi * 8 + ii)) * 64 + (wi * 8 + jj)) * 256;
    int fb = (tid & 1) * 4;
#pragma unroll
    for (int u = 0; u < 32; ++u) {
      int f = fb + u * 8;
      float4 d = *(const float4*)(src + f);
      __bf16 h0 = (__bf16)d.x, h1 = (__bf16)d.y, h2 = (__bf16)d.z, h3 = (__bf16)d.w;
      __bf16* dst = (__bf16*)&As[row][f];
      dst[0] = h0; dst[1] = h1; dst[2] = h2; dst[3] = h3;
    }
  }
  __syncthreads();  // the ONLY barrier

  int wid = tid >> 6, lane = tid & 63;
  int lg = lane >> 4, lr = lane & 15;
  int wr = wid >> 1, wc = wid & 1;
  unsigned short* Ts = (unsigned short*)(smem + 67584) + wid * 16 * 88;

  for (int nt = 0; nt < 6; ++nt) {
    f32x4 acc[4][4];
#pragma unroll
    for (int a = 0; a < 4; ++a)
#pragma unroll
      for (int b2 = 0; b2 < 4; ++b2) acc[a][b2] = (f32x4){0.f, 0.f, 0.f, 0.f};

    const unsigned short* bb2 = wqT + ((long)(nt * 128 + wc * 64)) * 256;
    for (int kk = 0; kk < 256; kk += 32) {
      bf16x8 af[4], bfr[4];
#pragma unroll
      for (int ni = 0; ni < 4; ++ni)
        bfr[ni] = *(const bf16x8*)(bb2 + (ni * 16 + lr) * 256 + kk + lg * 8);
#pragma unroll
      for (int mi = 0; mi < 4; ++mi)
        af[mi] = *(const bf16x8*)&As[wr * 64 + mi * 16 + lr][kk + lg * 8];
#pragma unroll
      for (int mi = 0; mi < 4; ++mi)
#pragma unroll
        for (int ni = 0; ni < 4; ++ni)
          acc[mi][ni] = __builtin_amdgcn_mfma_f32_16x16x32_bf16(af[mi], bfr[ni], acc[mi][ni], 0, 0, 0);
    }

    if (nt < 4) {
      // Q/K epilogue: per-wave LDS transpose -> 16B stores (256B segments)
      unsigned short* dst = (nt < 2) ? qo : ko;
      int head0 = (nt * 4 + wc * 2) & 7;
      long base0 = ((long)(bw * 8 + head0)) * 16384;
      long base1 = ((long)(bw * 8 + head0 + 1)) * 16384;
      int row = lane >> 2, c2 = lane & 3;
#pragma unroll
      for (int mi = 0; mi < 4; ++mi) {
#pragma unroll
        for (int ni = 0; ni < 4; ++ni)
#pragma unroll
          for (int r = 0; r < 4; ++r) {
            __bf16 hv = (__bf16)acc[mi][ni][r];
            Ts[(lg * 4 + r) * 88 + ni * 16 + lr] = __builtin_bit_cast(unsigned short, hv);
          }
        int n = n0 + wr * 64 + mi * 16 + row;
        long toff = ((long)((n >> 5) * 4 + c2)) * 256 + (n & 31) * 8;
        uint4 d0 = *(const uint4*)&Ts[row * 88 + c2 * 8];
        *(uint4*)&dst[base0 + toff] = d0;
        uint4 d1 = *(const uint4*)&Ts[row * 88 + 32 + c2 * 8];
        *(uint4*)&dst[base1 + toff] = d1;
      }
    } else {
      // V epilogue: fragment-chunk layout, packed 8B stores (round-8 verified)
#pragma unroll
      for (int ni = 0; ni < 4; ++ni) {
        int c = nt * 128 + wc * 64 + ni * 16 + lr;
        int d = c & 31;
        long base = ((long)(bw * 8 + ((c >> 5) & 7))) * 16384;
#pragma unroll
        for (int mi = 0; mi < 4; ++mi) {
          int m = n0 + wr * 64 + mi * 16 + lg * 4;
          long off = base + ((long)((m >> 5) * 4 + ((m >> 4) & 1) * 2 + ((m >> 3) & 1)) * 32 + d) * 8 + (m & 7);
          ushort4 w;
          __bf16 v0 = (__bf16)acc[mi][ni][0], v1 = (__bf16)acc[mi][ni][1];
          __bf16 v2 = (__bf16)acc[mi][ni][2], v3 = (__bf16)acc[mi][ni][3];
          w.x = __builtin_bit_cast(unsigned short, v0);
          w.y = __builtin_bit_cast(unsigned short, v1);
          w.z = __builtin_bit_cast(unsigned short, v2);
          w.w = __builtin_bit_cast(unsigned short, v3);
          *(ushort4*)&vo[off] = w;
        }
      }
    }
  }
}

// ---------------- kernel 2: attention per (window, head) ----------------
// grid 1024 blocks, 256 thr (4 waves x 128 q). LDS 64KB: K chunks @0, V chunks @32768.
__global__ __launch_bounds__(256, 2) void k_attn(
    const unsigned short* __restrict__ qs0, const unsigned short* __restrict__ ks0,
    const unsigned short* __restrict__ vs0, unsigned short* __restrict__ og) {
  extern __shared__ char smem[];
  int bh = blockIdx.x, tid = threadIdx.x;
  const unsigned short* kg = ks0 + (long)bh * 16384;
  const unsigned short* vg = vs0 + (long)bh * 16384;
#pragma unroll
  for (int i = 0; i < 8; ++i) {
    int ci = tid + i * 256;  // 16B chunks, 2048 per 32KB buffer
    *(uint4*)(smem + ci * 16) = *(const uint4*)(kg + ci * 8);
    *(uint4*)(smem + 32768 + ci * 16) = *(const uint4*)(vg + ci * 8);
  }
  __syncthreads();

  int wid = tid >> 6, lane = tid & 63;
  int l31 = lane & 31, h = lane >> 5;
  const unsigned short* qb = qs0 + (long)bh * 16384;
  unsigned short* ob = og + (long)bh * 16384;
  const f32x16 z16 = {0.f,0.f,0.f,0.f,0.f,0.f,0.f,0.f,0.f,0.f,0.f,0.f,0.f,0.f,0.f,0.f};

  // Q fragments (B-operand): lane supplies Q[q = qt*32 + l31][k = ks*16 + 8h + j]
  bf16x8 qf[4][2];
#pragma unroll
  for (int qt = 0; qt < 4; ++qt)
#pragma unroll
    for (int ks = 0; ks < 2; ++ks)
      qf[qt][ks] = *(const bf16x8*)(qb + ((wid * 4 + qt) * 4 + ks * 2 + h) * 256 + l31 * 8);

  f32x16 o[4];
  float ps[4];
#pragma unroll
  for (int qt = 0; qt < 4; ++qt) { o[qt] = z16; ps[qt] = 0.f; }

  for (int mt = 0; mt < 16; ++mt) {
    bf16x8 k0 = *(const bf16x8*)(smem + (mt * 4 + h) * 512 + l31 * 16);
    bf16x8 k1 = *(const bf16x8*)(smem + (mt * 4 + 2 + h) * 512 + l31 * 16);
    bf16x8 v0 = *(const bf16x8*)(smem + 32768 + (mt * 4 + h) * 512 + l31 * 16);
    bf16x8 v1 = *(const bf16x8*)(smem + 32768 + (mt * 4 + 2 + h) * 512 + l31 * 16);
#pragma unroll
    for (int qt = 0; qt < 4; ++qt) {
      // S^T[m][q]: C col=q=l31, row m = (r&3) + 8*(r>>2) + 4h
      f32x16 s = __builtin_amdgcn_mfma_f32_32x32x16_bf16(k0, qf[qt][0], z16, 0, 0, 0);
      s = __builtin_amdgcn_mfma_f32_32x32x16_bf16(k1, qf[qt][1], s, 0, 0, 0);
      float p[16];
#pragma unroll
      for (int r = 0; r < 16; ++r) p[r] = __builtin_amdgcn_exp2f(s[r]);
      ps[qt] += ((((p[0] + p[1]) + (p[2] + p[3])) + ((p[4] + p[5]) + (p[6] + p[7]))) +
                 (((p[8] + p[9]) + (p[10] + p[11])) + ((p[12] + p[13]) + (p[14] + p[15]))));
      unsigned w0 = pk2(p[0], p[1]),  w1 = pk2(p[2], p[3]);
      unsigned w2 = pk2(p[4], p[5]),  w3 = pk2(p[6], p[7]);
      unsigned w4 = pk2(p[8], p[9]),  w5 = pk2(p[10], p[11]);
      unsigned w6 = pk2(p[12], p[13]), w7 = pk2(p[14], p[15]);
      asm("v_permlane32_swap_b32 %0, %1" : "+v"(w0), "+v"(w2));
      asm("v_permlane32_swap_b32 %0, %1" : "+v"(w1), "+v"(w3));
      asm("v_permlane32_swap_b32 %0, %1" : "+v"(w4), "+v"(w6));
      asm("v_permlane32_swap_b32 %0, %1" : "+v"(w5), "+v"(w7));
      uint4 pb0u; pb0u.x = w0; pb0u.y = w1; pb0u.z = w2; pb0u.w = w3;
      uint4 pb1u; pb1u.x = w4; pb1u.y = w5; pb1u.z = w6; pb1u.w = w7;
      bf16x8 pb0 = __builtin_bit_cast(bf16x8, pb0u);
      bf16x8 pb1 = __builtin_bit_cast(bf16x8, pb1u);
      o[qt] = __builtin_amdgcn_mfma_f32_32x32x16_bf16(v0, pb0, o[qt], 0, 0, 0);
      o[qt] = __builtin_amdgcn_mfma_f32_32x32x16_bf16(v1, pb1, o[qt], 0, 0, 0);
    }
  }

#pragma unroll
  for (int qt = 0; qt < 4; ++qt) {
    float sum = ps[qt] + __shfl_xor(ps[qt], 32, 64);
    float rcp = 1.0f / sum;
    int q = (wid * 4 + qt) * 32 + l31;
#pragma unroll
    for (int s4 = 0; s4 < 4; ++s4) {
      __bf16 b0 = (__bf16)(o[qt][s4 * 4 + 0] * rcp);
      __bf16 b1 = (__bf16)(o[qt][s4 * 4 + 1] * rcp);
      __bf16 b2 = (__bf16)(o[qt][s4 * 4 + 2] * rcp);
      __bf16 b3 = (__bf16)(o[qt][s4 * 4 + 3] * rcp);
      ushort4 w;
      w.x = __builtin_bit_cast(unsigned short, b0);
      w.y = __builtin_bit_cast(unsigned short, b1);
      w.z = __builtin_bit_cast(unsigned short, b2);
      w.w = __builtin_bit_cast(unsigned short, b3);
      *(ushort4*)(ob + q * 32 + s4 * 8 + h * 4) = w;
    }
  }
}

// ---------------- kernel 3: proj GEMM + bias + window reverse ----------------
// Barrier-free: B-fragments direct from L2-resident wpT. LDS: As only (67584B).
__global__ __launch_bounds__(256, 2) void k_proj(
    const unsigned short* __restrict__ og, const unsigned short* __restrict__ wpT,
    const float* __restrict__ pb, float* __restrict__ out) {
  extern __shared__ char smem[];
  unsigned short (*As)[264] = (unsigned short (*)[264])smem;
  int tid = threadIdx.x;
  int mtile = blockIdx.x;
  int bw = mtile >> 2;
  int n0 = (mtile & 3) << 7;
  int bb = bw >> 6, hi = (bw >> 3) & 7, wi = bw & 7;

  {  // stage A from O layout [bw*8+head][n][32]
    int row = tid >> 1, hf = tid & 1;
#pragma unroll
    for (int h4 = 0; h4 < 4; ++h4) {
      int h = hf * 4 + h4;
      const uint4* asrc = (const uint4*)(og + (((long)(bw * 8 + h)) * NTOK + n0 + row) * DH);
      uint4 d0 = asrc[0], d1 = asrc[1], d2 = asrc[2], d3 = asrc[3];
      *(uint4*)&As[row][h * 32]      = d0;
      *(uint4*)&As[row][h * 32 + 8]  = d1;
      *(uint4*)&As[row][h * 32 + 16] = d2;
      *(uint4*)&As[row][h * 32 + 24] = d3;
    }
  }
  __syncthreads();  // the ONLY barrier

  int wid = tid >> 6, lane = tid & 63;
  int lg = lane >> 4, lr = lane & 15;
  int wr = wid >> 1, wc = wid & 1;

  for (int nt = 0; nt < 2; ++nt) {
    f32x4 acc[4][4];
#pragma unroll
    for (int a = 0; a < 4; ++a)
#pragma unroll
      for (int b2 = 0; b2 < 4; ++b2) acc[a][b2] = (f32x4){0.f, 0.f, 0.f, 0.f};

    const unsigned short* bb2 = wpT + ((long)(nt * 128 + wc * 64)) * 256;
    for (int kk = 0; kk < 256; kk += 32) {
      bf16x8 af[4], bfr[4];
#pragma unroll
      for (int ni = 0; ni < 4; ++ni)
        bfr[ni] = *(const bf16x8*)(bb2 + (ni * 16 + lr) * 256 + kk + lg * 8);
#pragma unroll
      for (int mi = 0; mi < 4; ++mi)
        af[mi] = *(const bf16x8*)&As[wr * 64 + mi * 16 + lr][kk + lg * 8];
#pragma unroll
      for (int mi = 0; mi < 4; ++mi)
#pragma unroll
        for (int ni = 0; ni < 4; ++ni)
          acc[mi][ni] = __builtin_amdgcn_mfma_f32_16x16x32_bf16(af[mi], bfr[ni], acc[mi][ni], 0, 0, 0);
    }
    // epilogue: bias + window reverse, coalesced fp32 (16 lanes -> 64B)
#pragma unroll
    for (int ni = 0; ni < 4; ++ni) {
      int c = nt * 128 + wc * 64 + ni * 16 + lr;
      float bias = pb[c];
#pragma unroll
      for (int mi = 0; mi < 4; ++mi) {
        int nbase = n0 + wr * 64 + mi * 16 + lg * 4;
#pragma unroll
        for (int r = 0; r < 4; ++r) {
          int n = nbase + r;
          int tt = n >> 6, ii = (n >> 3) & 7, jj = n & 7;
          long off = ((((long)(bb * 8 + tt)) * 64 + (hi * 8 + ii)) * 64 + (wi * 8 + jj)) * 256 + c;
          out[off] = acc[mi][ni][r] + bias;
        }
      }
    }
  }
}

extern "C" void kernel_launch(void* const* d_in, const int* in_sizes, int n_in,
                              void* d_out, int out_size, void* d_ws, size_t ws_size,
                              hipStream_t stream) {
  const float* x      = (const float*)d_in[0];
  const float* qkv_w  = (const float*)d_in[1];
  const float* proj_w = (const float*)d_in[2];
  const float* proj_b = (const float*)d_in[3];
  float* out = (float*)d_out;
  char* ws = (char*)d_ws;

  // workspace layout (bytes): wqT 393216 | wpT 131072 | Qs 32MiB | Ks 32MiB | Vs 32MiB | O 32MiB
  unsigned short* wqT = (unsigned short*)(ws);
  unsigned short* wpT = (unsigned short*)(ws + 393216);
  unsigned short* Q   = (unsigned short*)(ws + 524288);
  unsigned short* K   = (unsigned short*)(ws + 524288 + 1L * 33554432);
  unsigned short* V   = (unsigned short*)(ws + 524288 + 2L * 33554432);
  unsigned short* O   = (unsigned short*)(ws + 524288 + 3L * 33554432);

  (void)hipFuncSetAttribute((const void*)k_qkv,  hipFuncAttributeMaxDynamicSharedMemorySize, 78848);
  (void)hipFuncSetAttribute((const void*)k_attn, hipFuncAttributeMaxDynamicSharedMemorySize, 65536);
  (void)hipFuncSetAttribute((const void*)k_proj, hipFuncAttributeMaxDynamicSharedMemorySize, 67584);

  k_prep<<<256, 256, 0, stream>>>(qkv_w, proj_w, wqT, wpT);
  k_qkv<<<512, 256, 78848, stream>>>(x, wqT, Q, K, V);
  k_attn<<<1024, 256, 65536, stream>>>(Q, K, V, O);
  k_proj<<<512, 256, 67584, stream>>>(O, wpT, proj_b, out);
}

// Round 10
// 151.053 us; speedup vs baseline: 1.0341x; 1.0341x over previous
//
#include <hip/hip_runtime.h>

// Cuboid (windowed) self-attention, B=2,T=8,H=W=64,C=256, HEADS=8, WS=8.
// Bw = 128 windows, N = 512 tokens/window, dh = 32, bh = window*8+head (1024).
// k_prep: weightsT->bf16, fold scale*log2e into Q cols.
// k_qkv : window-partition + x@qkv_w. M-tile 64 (A [64][264] bf16, 33.8KB) ->
//         45KB LDS -> 3 blocks/CU (12 waves/CU). ONE barrier; B-fragments direct
//         from L2-resident wqT; per-wave col-tiles (3 x 64 cols), barrier-free loop.
//         Layouts (consumed by k_attn):
//         Qs/Ks[bh][t(16)][cb(4)][lane(32)][8]  (t=n>>5, cb=d>>3, lane=n&31, elem=d&7)
//         Vs[bh][mt(16)][kv(2)][h(2)][d(32)][8] (m = mt*32+kv*16+8h+j)
// k_attn: per bh, 4 waves x 128 q. K+V staged once in 64KB linear LDS.
//         32x32x16 MFMAs, S^T = K x Q^T; no-max softmax (shift-invariant, fp32-safe);
//         P -> PV B-operand via v_permlane32_swap_b32 (zero LDS); O in-register.
// k_proj: O@proj_w + bias, window reverse, fp32 out (round-8 B-staged form).

typedef __bf16 bf16x8 __attribute__((ext_vector_type(8)));
typedef float f32x4 __attribute__((ext_vector_type(4)));
typedef float f32x16 __attribute__((ext_vector_type(16)));

#define NTOK 512
#define DH 32
#define CDIM 256
#define C3 768

__device__ __forceinline__ unsigned short f2b(float f) {
  unsigned u = __builtin_bit_cast(unsigned, f);
  unsigned r = u + 0x7fffu + ((u >> 16) & 1u);   // RNE, inputs finite
  return (unsigned short)(r >> 16);
}

__device__ __forceinline__ unsigned pk2(float a, float b) {
  __bf16 x = (__bf16)a, y = (__bf16)b;
  return (unsigned)__builtin_bit_cast(unsigned short, x) |
         ((unsigned)__builtin_bit_cast(unsigned short, y) << 16);
}

// ---------------- kernel 0: weight prep ----------------
__global__ void k_prep(const float* __restrict__ qkv_w, const float* __restrict__ proj_w,
                       unsigned short* __restrict__ wqT, unsigned short* __restrict__ wpT) {
  const float QS = 0.2550540254f;  // 32^-0.5 * log2(e)
  int idx = blockIdx.x * 256 + threadIdx.x;
  int stride = gridDim.x * 256;
  for (int i = idx; i < C3 * CDIM; i += stride) {
    int n = i >> 8, kk = i & 255;
    float f = qkv_w[kk * C3 + n];
    if (n < 256) f *= QS;
    wqT[i] = f2b(f);
  }
  for (int i = idx; i < CDIM * CDIM; i += stride) {
    int n = i >> 8, kk = i & 255;
    wpT[i] = f2b(proj_w[kk * CDIM + n]);
  }
}

// ---------------- kernel 1: QKV GEMM (window partition fused) ----------------
// grid 1024 blocks, 256 thr. LDS: A [64][264] bf16 (33792B) +
// per-wave transpose tile [16][88] ushort (4 x 2816B = 11264B). Total 45056B.
__global__ __launch_bounds__(256, 3) void k_qkv(
    const float* __restrict__ x, const unsigned short* __restrict__ wqT,
    unsigned short* __restrict__ qo, unsigned short* __restrict__ ko,
    unsigned short* __restrict__ vo) {
  extern __shared__ char smem[];
  unsigned short (*As)[264] = (unsigned short (*)[264])smem;
  int tid = threadIdx.x;
  int mtile = blockIdx.x;
  int bw = mtile >> 3;
  int n0 = (mtile & 7) << 6;       // 64-row M-tile
  int bb = bw >> 6, hi = (bw >> 3) & 7, wi = bw & 7;

  {  // stage A: 64 rows gathered by window partition, fp32 -> bf16 (4 thr/row)
    int row = tid >> 2;
    int n = n0 + row;
    int tt = n >> 6, ii = (n >> 3) & 7, jj = n & 7;
    const float* src = x + ((((long)(bb * 8 + tt)) * 64 + (hi * 8 + ii)) * 64 + (wi * 8 + jj)) * 256;
    int fb = (tid & 3) * 4;
#pragma unroll
    for (int u = 0; u < 16; ++u) {
      int f = fb + u * 16;
      float4 d = *(const float4*)(src + f);
      __bf16 h0 = (__bf16)d.x, h1 = (__bf16)d.y, h2 = (__bf16)d.z, h3 = (__bf16)d.w;
      __bf16* dst = (__bf16*)&As[row][f];
      dst[0] = h0; dst[1] = h1; dst[2] = h2; dst[3] = h3;
    }
  }
  __syncthreads();  // the ONLY barrier

  int wid = tid >> 6, lane = tid & 63;
  int lg = lane >> 4, lr = lane & 15;
  unsigned short* Ts = (unsigned short*)(smem + 33792) + wid * 16 * 88;

  for (int it = 0; it < 3; ++it) {
    int c0 = (it * 4 + wid) * 64;    // 64-col tile; never straddles q/k/v boundary
    f32x4 acc[4][4];
#pragma unroll
    for (int a = 0; a < 4; ++a)
#pragma unroll
      for (int b2 = 0; b2 < 4; ++b2) acc[a][b2] = (f32x4){0.f, 0.f, 0.f, 0.f};

    const unsigned short* bb2 = wqT + (long)c0 * 256;
    for (int kk = 0; kk < 256; kk += 32) {
      bf16x8 af[4], bfr[4];
#pragma unroll
      for (int ni = 0; ni < 4; ++ni)
        bfr[ni] = *(const bf16x8*)(bb2 + (ni * 16 + lr) * 256 + kk + lg * 8);
#pragma unroll
      for (int mi = 0; mi < 4; ++mi)
        af[mi] = *(const bf16x8*)&As[mi * 16 + lr][kk + lg * 8];
#pragma unroll
      for (int mi = 0; mi < 4; ++mi)
#pragma unroll
        for (int ni = 0; ni < 4; ++ni)
          acc[mi][ni] = __builtin_amdgcn_mfma_f32_16x16x32_bf16(af[mi], bfr[ni], acc[mi][ni], 0, 0, 0);
    }

    int which = c0 >> 8;
    if (which < 2) {
      // Q/K epilogue: per-wave LDS transpose -> 16B stores (256B segments)
      unsigned short* dst = (which == 0) ? qo : ko;
      int head0 = (c0 >> 5) & 7;
      long base0 = ((long)(bw * 8 + head0)) * 16384;
      long base1 = ((long)(bw * 8 + head0 + 1)) * 16384;
      int trow = lane >> 2, c2 = lane & 3;
#pragma unroll
      for (int mi = 0; mi < 4; ++mi) {
#pragma unroll
        for (int ni = 0; ni < 4; ++ni)
#pragma unroll
          for (int r = 0; r < 4; ++r) {
            __bf16 hv = (__bf16)acc[mi][ni][r];
            Ts[(lg * 4 + r) * 88 + ni * 16 + lr] = __builtin_bit_cast(unsigned short, hv);
          }
        int n = n0 + mi * 16 + trow;
        long toff = ((long)((n >> 5) * 4 + c2)) * 256 + (n & 31) * 8;
        uint4 d0 = *(const uint4*)&Ts[trow * 88 + c2 * 8];
        *(uint4*)&dst[base0 + toff] = d0;
        uint4 d1 = *(const uint4*)&Ts[trow * 88 + 32 + c2 * 8];
        *(uint4*)&dst[base1 + toff] = d1;
      }
    } else {
      // V epilogue: fragment-chunk layout, packed 8B stores
#pragma unroll
      for (int ni = 0; ni < 4; ++ni) {
        int c = c0 + ni * 16 + lr;
        int d = c & 31;
        long base = ((long)(bw * 8 + ((c >> 5) & 7))) * 16384;
#pragma unroll
        for (int mi = 0; mi < 4; ++mi) {
          int m = n0 + mi * 16 + lg * 4;
          long off = base + ((long)((m >> 5) * 4 + ((m >> 4) & 1) * 2 + ((m >> 3) & 1)) * 32 + d) * 8 + (m & 7);
          ushort4 w;
          __bf16 v0 = (__bf16)acc[mi][ni][0], v1 = (__bf16)acc[mi][ni][1];
          __bf16 v2 = (__bf16)acc[mi][ni][2], v3 = (__bf16)acc[mi][ni][3];
          w.x = __builtin_bit_cast(unsigned short, v0);
          w.y = __builtin_bit_cast(unsigned short, v1);
          w.z = __builtin_bit_cast(unsigned short, v2);
          w.w = __builtin_bit_cast(unsigned short, v3);
          *(ushort4*)&vo[off] = w;
        }
      }
    }
  }
}

// ---------------- kernel 2: attention per (window, head) ----------------
// grid 1024 blocks, 256 thr (4 waves x 128 q). LDS 64KB: K chunks @0, V chunks @32768.
__global__ __launch_bounds__(256, 2) void k_attn(
    const unsigned short* __restrict__ qs0, const unsigned short* __restrict__ ks0,
    const unsigned short* __restrict__ vs0, unsigned short* __restrict__ og) {
  extern __shared__ char smem[];
  int bh = blockIdx.x, tid = threadIdx.x;
  const unsigned short* kg = ks0 + (long)bh * 16384;
  const unsigned short* vg = vs0 + (long)bh * 16384;
#pragma unroll
  for (int i = 0; i < 8; ++i) {
    int ci = tid + i * 256;  // 16B chunks, 2048 per 32KB buffer
    *(uint4*)(smem + ci * 16) = *(const uint4*)(kg + ci * 8);
    *(uint4*)(smem + 32768 + ci * 16) = *(const uint4*)(vg + ci * 8);
  }
  __syncthreads();

  int wid = tid >> 6, lane = tid & 63;
  int l31 = lane & 31, h = lane >> 5;
  const unsigned short* qb = qs0 + (long)bh * 16384;
  unsigned short* ob = og + (long)bh * 16384;
  const f32x16 z16 = {0.f,0.f,0.f,0.f,0.f,0.f,0.f,0.f,0.f,0.f,0.f,0.f,0.f,0.f,0.f,0.f};

  bf16x8 qf[4][2];
#pragma unroll
  for (int qt = 0; qt < 4; ++qt)
#pragma unroll
    for (int ks = 0; ks < 2; ++ks)
      qf[qt][ks] = *(const bf16x8*)(qb + ((wid * 4 + qt) * 4 + ks * 2 + h) * 256 + l31 * 8);

  f32x16 o[4];
  float ps[4];
#pragma unroll
  for (int qt = 0; qt < 4; ++qt) { o[qt] = z16; ps[qt] = 0.f; }

  for (int mt = 0; mt < 16; ++mt) {
    bf16x8 k0 = *(const bf16x8*)(smem + (mt * 4 + h) * 512 + l31 * 16);
    bf16x8 k1 = *(const bf16x8*)(smem + (mt * 4 + 2 + h) * 512 + l31 * 16);
    bf16x8 v0 = *(const bf16x8*)(smem + 32768 + (mt * 4 + h) * 512 + l31 * 16);
    bf16x8 v1 = *(const bf16x8*)(smem + 32768 + (mt * 4 + 2 + h) * 512 + l31 * 16);
#pragma unroll
    for (int qt = 0; qt < 4; ++qt) {
      f32x16 s = __builtin_amdgcn_mfma_f32_32x32x16_bf16(k0, qf[qt][0], z16, 0, 0, 0);
      s = __builtin_amdgcn_mfma_f32_32x32x16_bf16(k1, qf[qt][1], s, 0, 0, 0);
      float p[16];
#pragma unroll
      for (int r = 0; r < 16; ++r) p[r] = __builtin_amdgcn_exp2f(s[r]);
      ps[qt] += ((((p[0] + p[1]) + (p[2] + p[3])) + ((p[4] + p[5]) + (p[6] + p[7]))) +
                 (((p[8] + p[9]) + (p[10] + p[11])) + ((p[12] + p[13]) + (p[14] + p[15]))));
      unsigned w0 = pk2(p[0], p[1]),  w1 = pk2(p[2], p[3]);
      unsigned w2 = pk2(p[4], p[5]),  w3 = pk2(p[6], p[7]);
      unsigned w4 = pk2(p[8], p[9]),  w5 = pk2(p[10], p[11]);
      unsigned w6 = pk2(p[12], p[13]), w7 = pk2(p[14], p[15]);
      asm("v_permlane32_swap_b32 %0, %1" : "+v"(w0), "+v"(w2));
      asm("v_permlane32_swap_b32 %0, %1" : "+v"(w1), "+v"(w3));
      asm("v_permlane32_swap_b32 %0, %1" : "+v"(w4), "+v"(w6));
      asm("v_permlane32_swap_b32 %0, %1" : "+v"(w5), "+v"(w7));
      uint4 pb0u; pb0u.x = w0; pb0u.y = w1; pb0u.z = w2; pb0u.w = w3;
      uint4 pb1u; pb1u.x = w4; pb1u.y = w5; pb1u.z = w6; pb1u.w = w7;
      bf16x8 pb0 = __builtin_bit_cast(bf16x8, pb0u);
      bf16x8 pb1 = __builtin_bit_cast(bf16x8, pb1u);
      o[qt] = __builtin_amdgcn_mfma_f32_32x32x16_bf16(v0, pb0, o[qt], 0, 0, 0);
      o[qt] = __builtin_amdgcn_mfma_f32_32x32x16_bf16(v1, pb1, o[qt], 0, 0, 0);
    }
  }

#pragma unroll
  for (int qt = 0; qt < 4; ++qt) {
    float sum = ps[qt] + __shfl_xor(ps[qt], 32, 64);
    float rcp = 1.0f / sum;
    int q = (wid * 4 + qt) * 32 + l31;
#pragma unroll
    for (int s4 = 0; s4 < 4; ++s4) {
      __bf16 b0 = (__bf16)(o[qt][s4 * 4 + 0] * rcp);
      __bf16 b1 = (__bf16)(o[qt][s4 * 4 + 1] * rcp);
      __bf16 b2 = (__bf16)(o[qt][s4 * 4 + 2] * rcp);
      __bf16 b3 = (__bf16)(o[qt][s4 * 4 + 3] * rcp);
      ushort4 w;
      w.x = __builtin_bit_cast(unsigned short, b0);
      w.y = __builtin_bit_cast(unsigned short, b1);
      w.z = __builtin_bit_cast(unsigned short, b2);
      w.w = __builtin_bit_cast(unsigned short, b3);
      *(ushort4*)(ob + q * 32 + s4 * 8 + h * 4) = w;
    }
  }
}

// ---------------- kernel 3: proj GEMM + bias + window reverse ----------------
// Round-8 form: B LDS-staged. LDS: As 67584 + Bs 10240 = 77824.
__global__ __launch_bounds__(256, 2) void k_proj(
    const unsigned short* __restrict__ og, const unsigned short* __restrict__ wpT,
    const float* __restrict__ pb, float* __restrict__ out) {
  extern __shared__ char smem[];
  unsigned short (*As)[264] = (unsigned short (*)[264])smem;
  unsigned short (*Bs)[40]  = (unsigned short (*)[40])(smem + 128 * 264 * 2);
  int tid = threadIdx.x;
  int mtile = blockIdx.x;
  int bw = mtile >> 2;
  int n0 = (mtile & 3) << 7;
  int bb = bw >> 6, hi = (bw >> 3) & 7, wi = bw & 7;

  {  // stage A from O layout [bw*8+head][n][32]
    int row = tid >> 1, hf = tid & 1;
#pragma unroll
    for (int h4 = 0; h4 < 4; ++h4) {
      int h = hf * 4 + h4;
      const uint4* asrc = (const uint4*)(og + (((long)(bw * 8 + h)) * NTOK + n0 + row) * DH);
      uint4 d0 = asrc[0], d1 = asrc[1], d2 = asrc[2], d3 = asrc[3];
      *(uint4*)&As[row][h * 32]      = d0;
      *(uint4*)&As[row][h * 32 + 8]  = d1;
      *(uint4*)&As[row][h * 32 + 16] = d2;
      *(uint4*)&As[row][h * 32 + 24] = d3;
    }
  }
  __syncthreads();

  int wid = tid >> 6, lane = tid & 63;
  int lg = lane >> 4, lr = lane & 15;
  int wr = wid >> 1, wc = wid & 1;

  for (int nt = 0; nt < 2; ++nt) {
    f32x4 acc[4][4];
#pragma unroll
    for (int a = 0; a < 4; ++a)
#pragma unroll
      for (int b2 = 0; b2 < 4; ++b2) acc[a][b2] = (f32x4){0.f, 0.f, 0.f, 0.f};

    for (int kk = 0; kk < 256; kk += 32) {
      __syncthreads();
      {
        int brow = tid >> 1, bh2 = tid & 1;
        const uint4* bs = (const uint4*)(wpT + ((long)(nt * 128 + brow)) * 256 + kk + bh2 * 16);
        uint4 b0 = bs[0], b1 = bs[1];
        *(uint4*)&Bs[brow][bh2 * 16] = b0;
        *(uint4*)&Bs[brow][bh2 * 16 + 8] = b1;
      }
      __syncthreads();
      bf16x8 af[4], bfr[4];
#pragma unroll
      for (int mi = 0; mi < 4; ++mi)
        af[mi] = *(const bf16x8*)&As[wr * 64 + mi * 16 + lr][kk + lg * 8];
#pragma unroll
      for (int ni = 0; ni < 4; ++ni)
        bfr[ni] = *(const bf16x8*)&Bs[wc * 64 + ni * 16 + lr][lg * 8];
#pragma unroll
      for (int mi = 0; mi < 4; ++mi)
#pragma unroll
        for (int ni = 0; ni < 4; ++ni)
          acc[mi][ni] = __builtin_amdgcn_mfma_f32_16x16x32_bf16(af[mi], bfr[ni], acc[mi][ni], 0, 0, 0);
    }
    // epilogue: bias + window reverse, coalesced fp32 (16 lanes -> 64B)
#pragma unroll
    for (int ni = 0; ni < 4; ++ni) {
      int c = nt * 128 + wc * 64 + ni * 16 + lr;
      float bias = pb[c];
#pragma unroll
      for (int mi = 0; mi < 4; ++mi) {
        int nbase = n0 + wr * 64 + mi * 16 + lg * 4;
#pragma unroll
        for (int r = 0; r < 4; ++r) {
          int n = nbase + r;
          int tt = n >> 6, ii = (n >> 3) & 7, jj = n & 7;
          long off = ((((long)(bb * 8 + tt)) * 64 + (hi * 8 + ii)) * 64 + (wi * 8 + jj)) * 256 + c;
          out[off] = acc[mi][ni][r] + bias;
        }
      }
    }
  }
}

extern "C" void kernel_launch(void* const* d_in, const int* in_sizes, int n_in,
                              void* d_out, int out_size, void* d_ws, size_t ws_size,
                              hipStream_t stream) {
  const float* x      = (const float*)d_in[0];
  const float* qkv_w  = (const float*)d_in[1];
  const float* proj_w = (const float*)d_in[2];
  const float* proj_b = (const float*)d_in[3];
  float* out = (float*)d_out;
  char* ws = (char*)d_ws;

  // workspace layout (bytes): wqT 393216 | wpT 131072 | Qs 32MiB | Ks 32MiB | Vs 32MiB | O 32MiB
  unsigned short* wqT = (unsigned short*)(ws);
  unsigned short* wpT = (unsigned short*)(ws + 393216);
  unsigned short* Q   = (unsigned short*)(ws + 524288);
  unsigned short* K   = (unsigned short*)(ws + 524288 + 1L * 33554432);
  unsigned short* V   = (unsigned short*)(ws + 524288 + 2L * 33554432);
  unsigned short* O   = (unsigned short*)(ws + 524288 + 3L * 33554432);

  (void)hipFuncSetAttribute((const void*)k_qkv,  hipFuncAttributeMaxDynamicSharedMemorySize, 45056);
  (void)hipFuncSetAttribute((const void*)k_attn, hipFuncAttributeMaxDynamicSharedMemorySize, 65536);
  (void)hipFuncSetAttribute((const void*)k_proj, hipFuncAttributeMaxDynamicSharedMemorySize, 77824);

  k_prep<<<256, 256, 0, stream>>>(qkv_w, proj_w, wqT, wpT);
  k_qkv<<<1024, 256, 45056, stream>>>(x, wqT, Q, K, V);
  k_attn<<<1024, 256, 65536, stream>>>(Q, K, V, O);
  k_proj<<<512, 256, 77824, stream>>>(O, wpT, proj_b, out);
}

// Round 11
// 132.854 us; speedup vs baseline: 1.1757x; 1.1370x over previous
//
#include <hip/hip_runtime.h>

// Cuboid (windowed) self-attention, B=2,T=8,H=W=64,C=256, HEADS=8, WS=8.
// Bw = 128 windows, N = 512 tokens/window, dh = 32, bh = window*8+head (1024).
// k_prep: weights->bf16; wqT in MFMA-FRAGMENT order so k_qkv B-reads are 1KB
//         contiguous per wave:  wqT[t(12)][kkb(8)][ni(4)][lane(64)][8]
//         holds qkv_w[k=kkb*32+(lane>>4)*8+j][n=t*64+ni*16+(lane&15)] (*QS for q).
//         wpT stays row-major [n][k] (k_proj stages it through LDS).
// k_qkv : window-partition + x@qkv_w. M-tile 64, 45KB LDS (3 blocks/CU), ONE barrier;
//         B-fragments = coalesced 1KB loads from fragment-ordered wqT.
//         Output layouts (consumed by k_attn):
//         Qs/Ks[bh][t(16)][cb(4)][lane(32)][8]  (t=n>>5, cb=d>>3, lane=n&31, elem=d&7)
//         Vs[bh][mt(16)][kv(2)][h(2)][d(32)][8] (m = mt*32+kv*16+8h+j)
// k_attn: per bh, 4 waves x 128 q. K+V staged once in 64KB linear LDS.
//         32x32x16 MFMAs, S^T = K x Q^T; no-max softmax (shift-invariant, fp32-safe);
//         P -> PV B-operand via v_permlane32_swap_b32 (zero LDS); O in-register.
// k_proj: O@proj_w + bias, window reverse, fp32 out (B LDS-staged form).

typedef __bf16 bf16x8 __attribute__((ext_vector_type(8)));
typedef float f32x4 __attribute__((ext_vector_type(4)));
typedef float f32x16 __attribute__((ext_vector_type(16)));

#define NTOK 512
#define DH 32
#define CDIM 256
#define C3 768

__device__ __forceinline__ unsigned short f2b(float f) {
  unsigned u = __builtin_bit_cast(unsigned, f);
  unsigned r = u + 0x7fffu + ((u >> 16) & 1u);   // RNE, inputs finite
  return (unsigned short)(r >> 16);
}

__device__ __forceinline__ unsigned pk2(float a, float b) {
  __bf16 x = (__bf16)a, y = (__bf16)b;
  return (unsigned)__builtin_bit_cast(unsigned short, x) |
         ((unsigned)__builtin_bit_cast(unsigned short, y) << 16);
}

// ---------------- kernel 0: weight prep ----------------
__global__ void k_prep(const float* __restrict__ qkv_w, const float* __restrict__ proj_w,
                       unsigned short* __restrict__ wqT, unsigned short* __restrict__ wpT) {
  const float QS = 0.2550540254f;  // 32^-0.5 * log2(e)
  int idx = blockIdx.x * 256 + threadIdx.x;
  int stride = gridDim.x * 256;
  // wqT fragment order: chunk c = (((t*8+kkb)*4+ni)*4+lg)*16+lr, 8 elems (j) per chunk
  for (int c = idx; c < 24576; c += stride) {
    int lr = c & 15, lg = (c >> 4) & 3, ni = (c >> 6) & 3, kkb = (c >> 8) & 7, t = c >> 11;
    int n = t * 64 + ni * 16 + lr;       // qkv output column (0..767)
    int k0 = kkb * 32 + lg * 8;          // k (0..255)
    float sc = (n < 256) ? QS : 1.0f;
    unsigned short tmp[8];
#pragma unroll
    for (int j = 0; j < 8; ++j) tmp[j] = f2b(qkv_w[(long)(k0 + j) * C3 + n] * sc);
    *(uint4*)&wqT[(long)c * 8] = *(const uint4*)tmp;
  }
  // wpT row-major [n][k]
  for (int i = idx; i < CDIM * CDIM; i += stride) {
    int n = i >> 8, kk = i & 255;
    wpT[i] = f2b(proj_w[kk * CDIM + n]);
  }
}

// ---------------- kernel 1: QKV GEMM (window partition fused) ----------------
// grid 1024 blocks, 256 thr. LDS: A [64][264] bf16 (33792B) +
// per-wave transpose tile [16][88] ushort (4 x 2816B = 11264B). Total 45056B.
__global__ __launch_bounds__(256, 3) void k_qkv(
    const float* __restrict__ x, const unsigned short* __restrict__ wqT,
    unsigned short* __restrict__ qo, unsigned short* __restrict__ ko,
    unsigned short* __restrict__ vo) {
  extern __shared__ char smem[];
  unsigned short (*As)[264] = (unsigned short (*)[264])smem;
  int tid = threadIdx.x;
  int mtile = blockIdx.x;
  int bw = mtile >> 3;
  int n0 = (mtile & 7) << 6;       // 64-row M-tile
  int bb = bw >> 6, hi = (bw >> 3) & 7, wi = bw & 7;

  {  // stage A: 64 rows gathered by window partition, fp32 -> bf16 (4 thr/row)
    int row = tid >> 2;
    int n = n0 + row;
    int tt = n >> 6, ii = (n >> 3) & 7, jj = n & 7;
    const float* src = x + ((((long)(bb * 8 + tt)) * 64 + (hi * 8 + ii)) * 64 + (wi * 8 + jj)) * 256;
    int fb = (tid & 3) * 4;
#pragma unroll
    for (int u = 0; u < 16; ++u) {
      int f = fb + u * 16;
      float4 d = *(const float4*)(src + f);
      __bf16 h0 = (__bf16)d.x, h1 = (__bf16)d.y, h2 = (__bf16)d.z, h3 = (__bf16)d.w;
      __bf16* dst = (__bf16*)&As[row][f];
      dst[0] = h0; dst[1] = h1; dst[2] = h2; dst[3] = h3;
    }
  }
  __syncthreads();  // the ONLY barrier

  int wid = tid >> 6, lane = tid & 63;
  int lg = lane >> 4, lr = lane & 15;
  unsigned short* Ts = (unsigned short*)(smem + 33792) + wid * 16 * 88;

  for (int it = 0; it < 3; ++it) {
    int t = it * 4 + wid;            // 64-col N-panel id (0..11)
    int c0 = t * 64;
    f32x4 acc[4][4];
#pragma unroll
    for (int a = 0; a < 4; ++a)
#pragma unroll
      for (int b2 = 0; b2 < 4; ++b2) acc[a][b2] = (f32x4){0.f, 0.f, 0.f, 0.f};

    const unsigned short* bb2 = wqT + (long)t * 16384;  // fragment-ordered panel (32KB)
    for (int kk = 0; kk < 256; kk += 32) {
      int kkb = kk >> 5;
      bf16x8 af[4], bfr[4];
#pragma unroll
      for (int ni = 0; ni < 4; ++ni)
        bfr[ni] = *(const bf16x8*)(bb2 + (long)((kkb * 4 + ni) * 64 + lane) * 8);
#pragma unroll
      for (int mi = 0; mi < 4; ++mi)
        af[mi] = *(const bf16x8*)&As[mi * 16 + lr][kk + lg * 8];
#pragma unroll
      for (int mi = 0; mi < 4; ++mi)
#pragma unroll
        for (int ni = 0; ni < 4; ++ni)
          acc[mi][ni] = __builtin_amdgcn_mfma_f32_16x16x32_bf16(af[mi], bfr[ni], acc[mi][ni], 0, 0, 0);
    }

    int which = c0 >> 8;
    if (which < 2) {
      // Q/K epilogue: per-wave LDS transpose -> 16B stores (256B segments)
      unsigned short* dst = (which == 0) ? qo : ko;
      int head0 = (c0 >> 5) & 7;
      long base0 = ((long)(bw * 8 + head0)) * 16384;
      long base1 = ((long)(bw * 8 + head0 + 1)) * 16384;
      int trow = lane >> 2, c2 = lane & 3;
#pragma unroll
      for (int mi = 0; mi < 4; ++mi) {
#pragma unroll
        for (int ni = 0; ni < 4; ++ni)
#pragma unroll
          for (int r = 0; r < 4; ++r) {
            __bf16 hv = (__bf16)acc[mi][ni][r];
            Ts[(lg * 4 + r) * 88 + ni * 16 + lr] = __builtin_bit_cast(unsigned short, hv);
          }
        int n = n0 + mi * 16 + trow;
        long toff = ((long)((n >> 5) * 4 + c2)) * 256 + (n & 31) * 8;
        uint4 d0 = *(const uint4*)&Ts[trow * 88 + c2 * 8];
        *(uint4*)&dst[base0 + toff] = d0;
        uint4 d1 = *(const uint4*)&Ts[trow * 88 + 32 + c2 * 8];
        *(uint4*)&dst[base1 + toff] = d1;
      }
    } else {
      // V epilogue: fragment-chunk layout, packed 8B stores
#pragma unroll
      for (int ni = 0; ni < 4; ++ni) {
        int c = c0 + ni * 16 + lr;
        int d = c & 31;
        long base = ((long)(bw * 8 + ((c >> 5) & 7))) * 16384;
#pragma unroll
        for (int mi = 0; mi < 4; ++mi) {
          int m = n0 + mi * 16 + lg * 4;
          long off = base + ((long)((m >> 5) * 4 + ((m >> 4) & 1) * 2 + ((m >> 3) & 1)) * 32 + d) * 8 + (m & 7);
          ushort4 w;
          __bf16 v0 = (__bf16)acc[mi][ni][0], v1 = (__bf16)acc[mi][ni][1];
          __bf16 v2 = (__bf16)acc[mi][ni][2], v3 = (__bf16)acc[mi][ni][3];
          w.x = __builtin_bit_cast(unsigned short, v0);
          w.y = __builtin_bit_cast(unsigned short, v1);
          w.z = __builtin_bit_cast(unsigned short, v2);
          w.w = __builtin_bit_cast(unsigned short, v3);
          *(ushort4*)&vo[off] = w;
        }
      }
    }
  }
}

// ---------------- kernel 2: attention per (window, head) ----------------
// grid 1024 blocks, 256 thr (4 waves x 128 q). LDS 64KB: K chunks @0, V chunks @32768.
__global__ __launch_bounds__(256, 2) void k_attn(
    const unsigned short* __restrict__ qs0, const unsigned short* __restrict__ ks0,
    const unsigned short* __restrict__ vs0, unsigned short* __restrict__ og) {
  extern __shared__ char smem[];
  int bh = blockIdx.x, tid = threadIdx.x;
  const unsigned short* kg = ks0 + (long)bh * 16384;
  const unsigned short* vg = vs0 + (long)bh * 16384;
#pragma unroll
  for (int i = 0; i < 8; ++i) {
    int ci = tid + i * 256;  // 16B chunks, 2048 per 32KB buffer
    *(uint4*)(smem + ci * 16) = *(const uint4*)(kg + ci * 8);
    *(uint4*)(smem + 32768 + ci * 16) = *(const uint4*)(vg + ci * 8);
  }
  __syncthreads();

  int wid = tid >> 6, lane = tid & 63;
  int l31 = lane & 31, h = lane >> 5;
  const unsigned short* qb = qs0 + (long)bh * 16384;
  unsigned short* ob = og + (long)bh * 16384;
  const f32x16 z16 = {0.f,0.f,0.f,0.f,0.f,0.f,0.f,0.f,0.f,0.f,0.f,0.f,0.f,0.f,0.f,0.f};

  bf16x8 qf[4][2];
#pragma unroll
  for (int qt = 0; qt < 4; ++qt)
#pragma unroll
    for (int ks = 0; ks < 2; ++ks)
      qf[qt][ks] = *(const bf16x8*)(qb + ((wid * 4 + qt) * 4 + ks * 2 + h) * 256 + l31 * 8);

  f32x16 o[4];
  float ps[4];
#pragma unroll
  for (int qt = 0; qt < 4; ++qt) { o[qt] = z16; ps[qt] = 0.f; }

  for (int mt = 0; mt < 16; ++mt) {
    bf16x8 k0 = *(const bf16x8*)(smem + (mt * 4 + h) * 512 + l31 * 16);
    bf16x8 k1 = *(const bf16x8*)(smem + (mt * 4 + 2 + h) * 512 + l31 * 16);
    bf16x8 v0 = *(const bf16x8*)(smem + 32768 + (mt * 4 + h) * 512 + l31 * 16);
    bf16x8 v1 = *(const bf16x8*)(smem + 32768 + (mt * 4 + 2 + h) * 512 + l31 * 16);
#pragma unroll
    for (int qt = 0; qt < 4; ++qt) {
      f32x16 s = __builtin_amdgcn_mfma_f32_32x32x16_bf16(k0, qf[qt][0], z16, 0, 0, 0);
      s = __builtin_amdgcn_mfma_f32_32x32x16_bf16(k1, qf[qt][1], s, 0, 0, 0);
      float p[16];
#pragma unroll
      for (int r = 0; r < 16; ++r) p[r] = __builtin_amdgcn_exp2f(s[r]);
      ps[qt] += ((((p[0] + p[1]) + (p[2] + p[3])) + ((p[4] + p[5]) + (p[6] + p[7]))) +
                 (((p[8] + p[9]) + (p[10] + p[11])) + ((p[12] + p[13]) + (p[14] + p[15]))));
      unsigned w0 = pk2(p[0], p[1]),  w1 = pk2(p[2], p[3]);
      unsigned w2 = pk2(p[4], p[5]),  w3 = pk2(p[6], p[7]);
      unsigned w4 = pk2(p[8], p[9]),  w5 = pk2(p[10], p[11]);
      unsigned w6 = pk2(p[12], p[13]), w7 = pk2(p[14], p[15]);
      asm("v_permlane32_swap_b32 %0, %1" : "+v"(w0), "+v"(w2));
      asm("v_permlane32_swap_b32 %0, %1" : "+v"(w1), "+v"(w3));
      asm("v_permlane32_swap_b32 %0, %1" : "+v"(w4), "+v"(w6));
      asm("v_permlane32_swap_b32 %0, %1" : "+v"(w5), "+v"(w7));
      uint4 pb0u; pb0u.x = w0; pb0u.y = w1; pb0u.z = w2; pb0u.w = w3;
      uint4 pb1u; pb1u.x = w4; pb1u.y = w5; pb1u.z = w6; pb1u.w = w7;
      bf16x8 pb0 = __builtin_bit_cast(bf16x8, pb0u);
      bf16x8 pb1 = __builtin_bit_cast(bf16x8, pb1u);
      o[qt] = __builtin_amdgcn_mfma_f32_32x32x16_bf16(v0, pb0, o[qt], 0, 0, 0);
      o[qt] = __builtin_amdgcn_mfma_f32_32x32x16_bf16(v1, pb1, o[qt], 0, 0, 0);
    }
  }

#pragma unroll
  for (int qt = 0; qt < 4; ++qt) {
    float sum = ps[qt] + __shfl_xor(ps[qt], 32, 64);
    float rcp = 1.0f / sum;
    int q = (wid * 4 + qt) * 32 + l31;
#pragma unroll
    for (int s4 = 0; s4 < 4; ++s4) {
      __bf16 b0 = (__bf16)(o[qt][s4 * 4 + 0] * rcp);
      __bf16 b1 = (__bf16)(o[qt][s4 * 4 + 1] * rcp);
      __bf16 b2 = (__bf16)(o[qt][s4 * 4 + 2] * rcp);
      __bf16 b3 = (__bf16)(o[qt][s4 * 4 + 3] * rcp);
      ushort4 w;
      w.x = __builtin_bit_cast(unsigned short, b0);
      w.y = __builtin_bit_cast(unsigned short, b1);
      w.z = __builtin_bit_cast(unsigned short, b2);
      w.w = __builtin_bit_cast(unsigned short, b3);
      *(ushort4*)(ob + q * 32 + s4 * 8 + h * 4) = w;
    }
  }
}

// ---------------- kernel 3: proj GEMM + bias + window reverse ----------------
// B LDS-staged. LDS: As 67584 + Bs 10240 = 77824.
__global__ __launch_bounds__(256, 2) void k_proj(
    const unsigned short* __restrict__ og, const unsigned short* __restrict__ wpT,
    const float* __restrict__ pb, float* __restrict__ out) {
  extern __shared__ char smem[];
  unsigned short (*As)[264] = (unsigned short (*)[264])smem;
  unsigned short (*Bs)[40]  = (unsigned short (*)[40])(smem + 128 * 264 * 2);
  int tid = threadIdx.x;
  int mtile = blockIdx.x;
  int bw = mtile >> 2;
  int n0 = (mtile & 3) << 7;
  int bb = bw >> 6, hi = (bw >> 3) & 7, wi = bw & 7;

  {  // stage A from O layout [bw*8+head][n][32]
    int row = tid >> 1, hf = tid & 1;
#pragma unroll
    for (int h4 = 0; h4 < 4; ++h4) {
      int h = hf * 4 + h4;
      const uint4* asrc = (const uint4*)(og + (((long)(bw * 8 + h)) * NTOK + n0 + row) * DH);
      uint4 d0 = asrc[0], d1 = asrc[1], d2 = asrc[2], d3 = asrc[3];
      *(uint4*)&As[row][h * 32]      = d0;
      *(uint4*)&As[row][h * 32 + 8]  = d1;
      *(uint4*)&As[row][h * 32 + 16] = d2;
      *(uint4*)&As[row][h * 32 + 24] = d3;
    }
  }
  __syncthreads();

  int wid = tid >> 6, lane = tid & 63;
  int lg = lane >> 4, lr = lane & 15;
  int wr = wid >> 1, wc = wid & 1;

  for (int nt = 0; nt < 2; ++nt) {
    f32x4 acc[4][4];
#pragma unroll
    for (int a = 0; a < 4; ++a)
#pragma unroll
      for (int b2 = 0; b2 < 4; ++b2) acc[a][b2] = (f32x4){0.f, 0.f, 0.f, 0.f};

    for (int kk = 0; kk < 256; kk += 32) {
      __syncthreads();
      {
        int brow = tid >> 1, bh2 = tid & 1;
        const uint4* bs = (const uint4*)(wpT + ((long)(nt * 128 + brow)) * 256 + kk + bh2 * 16);
        uint4 b0 = bs[0], b1 = bs[1];
        *(uint4*)&Bs[brow][bh2 * 16] = b0;
        *(uint4*)&Bs[brow][bh2 * 16 + 8] = b1;
      }
      __syncthreads();
      bf16x8 af[4], bfr[4];
#pragma unroll
      for (int mi = 0; mi < 4; ++mi)
        af[mi] = *(const bf16x8*)&As[wr * 64 + mi * 16 + lr][kk + lg * 8];
#pragma unroll
      for (int ni = 0; ni < 4; ++ni)
        bfr[ni] = *(const bf16x8*)&Bs[wc * 64 + ni * 16 + lr][lg * 8];
#pragma unroll
      for (int mi = 0; mi < 4; ++mi)
#pragma unroll
        for (int ni = 0; ni < 4; ++ni)
          acc[mi][ni] = __builtin_amdgcn_mfma_f32_16x16x32_bf16(af[mi], bfr[ni], acc[mi][ni], 0, 0, 0);
    }
    // epilogue: bias + window reverse, coalesced fp32 (16 lanes -> 64B)
#pragma unroll
    for (int ni = 0; ni < 4; ++ni) {
      int c = nt * 128 + wc * 64 + ni * 16 + lr;
      float bias = pb[c];
#pragma unroll
      for (int mi = 0; mi < 4; ++mi) {
        int nbase = n0 + wr * 64 + mi * 16 + lg * 4;
#pragma unroll
        for (int r = 0; r < 4; ++r) {
          int n = nbase + r;
          int tt = n >> 6, ii = (n >> 3) & 7, jj = n & 7;
          long off = ((((long)(bb * 8 + tt)) * 64 + (hi * 8 + ii)) * 64 + (wi * 8 + jj)) * 256 + c;
          out[off] = acc[mi][ni][r] + bias;
        }
      }
    }
  }
}

extern "C" void kernel_launch(void* const* d_in, const int* in_sizes, int n_in,
                              void* d_out, int out_size, void* d_ws, size_t ws_size,
                              hipStream_t stream) {
  const float* x      = (const float*)d_in[0];
  const float* qkv_w  = (const float*)d_in[1];
  const float* proj_w = (const float*)d_in[2];
  const float* proj_b = (const float*)d_in[3];
  float* out = (float*)d_out;
  char* ws = (char*)d_ws;

  // workspace layout (bytes): wqT 393216 | wpT 131072 | Qs 32MiB | Ks 32MiB | Vs 32MiB | O 32MiB
  unsigned short* wqT = (unsigned short*)(ws);
  unsigned short* wpT = (unsigned short*)(ws + 393216);
  unsigned short* Q   = (unsigned short*)(ws + 524288);
  unsigned short* K   = (unsigned short*)(ws + 524288 + 1L * 33554432);
  unsigned short* V   = (unsigned short*)(ws + 524288 + 2L * 33554432);
  unsigned short* O   = (unsigned short*)(ws + 524288 + 3L * 33554432);

  (void)hipFuncSetAttribute((const void*)k_qkv,  hipFuncAttributeMaxDynamicSharedMemorySize, 45056);
  (void)hipFuncSetAttribute((const void*)k_attn, hipFuncAttributeMaxDynamicSharedMemorySize, 65536);
  (void)hipFuncSetAttribute((const void*)k_proj, hipFuncAttributeMaxDynamicSharedMemorySize, 77824);

  k_prep<<<256, 256, 0, stream>>>(qkv_w, proj_w, wqT, wpT);
  k_qkv<<<1024, 256, 45056, stream>>>(x, wqT, Q, K, V);
  k_attn<<<1024, 256, 65536, stream>>>(Q, K, V, O);
  k_proj<<<512, 256, 77824, stream>>>(O, wpT, proj_b, out);
}